// Round 1
// baseline (224.536 us; speedup 1.0000x reference)
//
#include <hip/hip_runtime.h>
#include <math.h>

#define NN 1024
#define HD 64
#define NL 3

// ws layout (floats): te[64] | tc[3*64] | ec[64] | hi[N*64] | hj[N*64]
#define WTE 0
#define WTC 64
#define WEC 256
#define WHI 320
#define WHJ (320 + NN*HD)

__device__ __forceinline__ float fsilu(float x) {
    float e = __expf(-x);
    return x * __builtin_amdgcn_rcpf(1.0f + e);
}
__device__ __forceinline__ float fsigmoid(float x) {
    float e = __expf(-x);
    return __builtin_amdgcn_rcpf(1.0f + e);
}

// ---------------- kernel 1: time embedding + per-layer te-contributions ----
__global__ void k_time(const int* __restrict__ tp,
                       const float* __restrict__ tw1, const float* __restrict__ tb1,
                       const float* __restrict__ tw2, const float* __restrict__ tb2,
                       const float* __restrict__ mw,  const float* __restrict__ mb,
                       const float* __restrict__ hw1, const float* __restrict__ hb1,
                       float* __restrict__ ws)
{
    __shared__ float s_raw[HD], s_x[HD], s_te[HD];
    const int h = threadIdx.x;
    const float tv = (float)(*tp);
    const int hf = h & 31;
    const float fr = expf((float)hf * (-logf(10000.0f) / 31.0f));
    const float ang = tv * fr;
    s_raw[h] = (h < 32) ? sinf(ang) : cosf(ang);
    __syncthreads();
    float a = tb1[h];
    for (int k = 0; k < HD; ++k) a = fmaf(s_raw[k], tw1[k*HD + h], a);
    s_x[h] = fsilu(a);
    __syncthreads();
    float te = tb2[h];
    for (int k = 0; k < HD; ++k) te = fmaf(s_x[k], tw2[k*HD + h], te);
    s_te[h] = te;
    ws[WTE + h] = te;
    __syncthreads();
    // tc[l][h] = mb[l][h] + sum_k te[k]*mw[l][128+k][h]   (te_b block of mp layer)
    for (int l = 0; l < NL; ++l) {
        float t2 = mb[l*HD + h];
        for (int k = 0; k < HD; ++k)
            t2 = fmaf(s_te[k], mw[(l*3*HD + 2*HD + k)*HD + h], t2);
        ws[WTC + l*HD + h] = t2;
    }
    // ec[h] = hb1[h] + sum_k te[k]*hw1[64+k][h]          (te_b block of eps head)
    float e = hb1[h];
    for (int k = 0; k < HD; ++k) e = fmaf(s_te[k], hw1[(HD + k)*HD + h], e);
    ws[WEC + h] = e;
}

// ---------------- kernel 2: per-row fused 3-layer message passing ----------
__global__ __launch_bounds__(256) void k_main(
    const float* __restrict__ pos, const float* __restrict__ adj,
    const float* __restrict__ nmask,
    const float* __restrict__ pw, const float* __restrict__ pb,
    const float* __restrict__ ew1, const float* __restrict__ eb1,
    const float* __restrict__ ew2, const float* __restrict__ eb2,
    const float* __restrict__ mw,
    const float* __restrict__ aw1,
    const float* __restrict__ hw1,
    const float* __restrict__ hw2, const float* __restrict__ hb2,
    float* __restrict__ ws, float* __restrict__ out)
{
    __shared__ float4 s_ef[NN];       // compacted (dx,dy,dz,dist) 16KB
    __shared__ float  s_cval[NN];     // compacted adj values       4KB
    __shared__ float  s_red[1024];    // reduction scratch          4KB
    __shared__ float  s_s[HD], s_msg[HD], s_h[HD], s_eu[HD];
    __shared__ int    s_nnz;
    __shared__ float  s_deg;

    const int i = blockIdx.x;
    const int t = threadIdx.x;
    const int lane = t & 63;

    if (t == 0) s_nnz = 0;
    __syncthreads();

    // ---- setup: compact nonzero adj entries + rel/dist, row degree, h0 ----
    const float pix = pos[3*i+0], piy = pos[3*i+1], piz = pos[3*i+2];
    float degp = 0.0f;
    for (int base = 0; base < NN; base += 256) {
        const int j = base + t;
        const float av = adj[i*NN + j];
        degp += av;
        const bool nz = (av != 0.0f);
        const unsigned long long m = __ballot(nz);
        int wb = 0;
        if (lane == 0) wb = atomicAdd(&s_nnz, __popcll(m));
        wb = __shfl(wb, 0);
        if (nz) {
            const int k = wb + __popcll(m & ((1ull << lane) - 1ull));
            const float dx = pix - pos[3*j+0];
            const float dy = piy - pos[3*j+1];
            const float dz = piz - pos[3*j+2];
            const float d = sqrtf(dx*dx + dy*dy + dz*dz);
            s_ef[k] = make_float4(dx, dy, dz, d);
            s_cval[k] = av;
        }
    }
    s_red[t] = degp;
    __syncthreads();
    if (t < HD) {  // h0 = pos@pw + pb + te
        float a = pb[t] + ws[WTE + t];
        a = fmaf(pix, pw[0*HD + t], a);
        a = fmaf(piy, pw[1*HD + t], a);
        a = fmaf(piz, pw[2*HD + t], a);
        s_h[t] = a;
    }
    if (t < 16) {
        float d = 0.0f;
        for (int k = 0; k < 16; ++k) d += s_red[t*16 + k];
        s_eu[t] = d;
    }
    __syncthreads();
    if (t == 0) {
        float d = 0.0f;
        for (int k = 0; k < 16; ++k) d += s_eu[k];
        s_deg = d;
    }
    const int nnz = s_nnz;
    const int jj = t >> 4;        // 16 j-groups
    const int hh = t & 15;        // 16 h-groups of 4
    const int hb = hh << 2;
    const int q  = t >> 6;        // wave id
    const int h2 = t & 63;

    for (int l = 0; l < NL; ++l) {
        // per-thread loop-invariant edge-MLP weights (4 h columns)
        float w0[4], w1[4], w2[4], w3[4], bb[4];
        #pragma unroll
        for (int r = 0; r < 4; ++r) {
            w0[r] = ew1[(l*4 + 0)*HD + hb + r];
            w1[r] = ew1[(l*4 + 1)*HD + hb + r];
            w2[r] = ew1[(l*4 + 2)*HD + hb + r];
            w3[r] = ew1[(l*4 + 3)*HD + hb + r];
            bb[r] = eb1[l*HD + hb + r];
        }
        // phase 1: s[h] = sum_{nz j} adj * silu(ef_in @ ew1 + eb1)
        float acc[4] = {0.f, 0.f, 0.f, 0.f};
        for (int k = jj; k < nnz; k += 16) {
            const float4 ef = s_ef[k];
            const float av = s_cval[k];
            #pragma unroll
            for (int r = 0; r < 4; ++r) {
                float g = fmaf(ef.x, w0[r], bb[r]);
                g = fmaf(ef.y, w1[r], g);
                g = fmaf(ef.z, w2[r], g);
                g = fmaf(ef.w, w3[r], g);
                acc[r] = fmaf(av, fsilu(g), acc[r]);
            }
        }
        *reinterpret_cast<float4*>(&s_red[jj*HD + hb]) =
            make_float4(acc[0], acc[1], acc[2], acc[3]);
        __syncthreads();                                   // S1
        if (t < HD) {
            float s = 0.0f;
            #pragma unroll
            for (int ww = 0; ww < 16; ++ww) s += s_red[ww*HD + t];
            s_s[t] = s;
        }
        __syncthreads();                                   // S2
        // phase 2a: msg = s@ew2 + deg*eb2 + h   (256-thread split over k)
        {
            float pm = 0.0f;
            #pragma unroll
            for (int kk = 0; kk < 16; ++kk) {
                const int k = q*16 + kk;
                pm = fmaf(s_s[k], ew2[(l*HD + k)*HD + h2], pm);
            }
            s_red[q*HD + h2] = pm;
        }
        __syncthreads();                                   // S3
        if (t < HD) {
            float m = s_red[t] + s_red[HD + t] + s_red[2*HD + t] + s_red[3*HD + t];
            m = fmaf(s_deg, eb2[l*HD + t], m);
            m += s_h[t];
            s_msg[t] = m;
        }
        __syncthreads();                                   // S4
        // phase 2b: h = silu([h,msg]@mw[0:128] + tc)      (256-thread split)
        {
            float ph = 0.0f;
            #pragma unroll
            for (int kk = 0; kk < 32; ++kk) {
                const int row = q*32 + kk;
                const float x = (q < 2) ? s_h[row] : s_msg[row - HD];
                ph = fmaf(x, mw[(l*3*HD + row)*HD + h2], ph);
            }
            s_red[q*HD + h2] = ph;
        }
        __syncthreads();                                   // S5
        if (t < HD) {
            float a = ws[WTC + l*HD + t];
            a += s_red[t] + s_red[HD + t] + s_red[2*HD + t] + s_red[3*HD + t];
            s_h[t] = fsilu(a);
        }
        __syncthreads();                                   // S6
    }

    // ---- tail: eps head + hi/hj projections for adj head ----
    if (t < HD) {
        float a = ws[WEC + t];
        for (int k = 0; k < HD; ++k) a = fmaf(s_h[k], hw1[k*HD + t], a);
        s_eu[t] = fsilu(a);
        float a1 = 0.f, a2 = 0.f;
        for (int k = 0; k < HD; ++k) {
            a1 = fmaf(s_h[k], aw1[k*HD + t], a1);
            a2 = fmaf(s_h[k], aw1[(HD + k)*HD + t], a2);
        }
        ws[WHI + i*HD + t] = a1;
        ws[WHJ + i*HD + t] = a2;
    }
    __syncthreads();                                       // S7
    if (t < 3) {
        float e = hb2[t];
        for (int k = 0; k < HD; ++k) e = fmaf(s_eu[k], hw2[k*3 + t], e);
        out[NN*NN + i*3 + t] = e * nmask[i];
    }
}

// ---------------- kernel 3: adj head on unordered tile pairs ---------------
__global__ __launch_bounds__(256) void k_adj(
    const float* __restrict__ ws, const float* __restrict__ nmask,
    const float* __restrict__ ab1, const float* __restrict__ aw2,
    const float* __restrict__ ab2, float* __restrict__ out)
{
    __shared__ float4 s_hiI[16*17], s_hjJ[16*17], s_hiJ[16*17], s_hjI[16*17];
    __shared__ float s_L1[16][17], s_L2[16][17];
    const int T = NN / 16;  // 64 tiles per side
    const int b = blockIdx.x;
    // decode unordered pair (I <= J) from linear index b
    int I = (int)((2.0*T + 1.0 -
                   sqrt((2.0*T + 1.0)*(2.0*T + 1.0) - 8.0*(double)b)) * 0.5);
    if (I < 0) I = 0; if (I > T-1) I = T-1;
    while (I+1 <= T-1 && ((I+1)*T - ((I+1)*I)/2) <= b) ++I;
    while (I > 0 && (I*T - (I*(I-1))/2) > b) --I;
    const int J = I + (b - (I*T - (I*(I-1))/2));
    const int I0 = I*16, J0 = J*16;
    const int t = threadIdx.x;
    const float* hi = ws + WHI;
    const float* hj = ws + WHJ;
    // stage hi/hj rows for both tiles (padded [16][17] float4 -> conflict-free)
    for (int idx = t; idx < 4*16*16; idx += 256) {
        const int arr = idx >> 8, rem = idx & 255, r = rem >> 4, qq = rem & 15;
        const float* src = (arr == 0 || arr == 2) ? hi : hj;
        const int rowt = (arr == 0 || arr == 3) ? I0 : J0;
        const float4 v = *reinterpret_cast<const float4*>(src + (rowt + r)*HD + qq*4);
        float4* dst = (arr == 0) ? s_hiI : (arr == 1) ? s_hjJ
                     : (arr == 2) ? s_hiJ : s_hjI;
        dst[r*17 + qq] = v;
    }
    __syncthreads();
    const int r = t >> 4, c = t & 15;
    float l1 = 0.f, l2 = 0.f;
    for (int hq = 0; hq < 16; ++hq) {
        const float4 aI = s_hiI[r*17 + hq];
        const float4 bJ = s_hjJ[c*17 + hq];
        const float4 aJ = s_hiJ[r*17 + hq];
        const float4 bI = s_hjI[c*17 + hq];
        const float4 ab = *reinterpret_cast<const float4*>(ab1 + hq*4);
        const float4 w  = *reinterpret_cast<const float4*>(aw2 + hq*4);
        l1 += fsilu(aI.x + bJ.x + ab.x)*w.x + fsilu(aI.y + bJ.y + ab.y)*w.y
            + fsilu(aI.z + bJ.z + ab.z)*w.z + fsilu(aI.w + bJ.w + ab.w)*w.w;
        l2 += fsilu(aJ.x + bI.x + ab.x)*w.x + fsilu(aJ.y + bI.y + ab.y)*w.y
            + fsilu(aJ.z + bI.z + ab.z)*w.z + fsilu(aJ.w + bI.w + ab.w)*w.w;
    }
    const float b2 = ab2[0];
    s_L1[r][c] = l1 + b2;   // logits(I0+r, J0+c)
    s_L2[r][c] = l2 + b2;   // logits(J0+r, I0+c)
    __syncthreads();
    const float v1 = 0.5f*(s_L1[r][c] + s_L2[c][r]);
    const float v2 = 0.5f*(s_L2[r][c] + s_L1[c][r]);
    const int gi1 = I0 + r, gj1 = J0 + c;
    out[gi1*NN + gj1] = fsigmoid(v1) * nmask[gi1] * nmask[gj1];
    const int gi2 = J0 + r, gj2 = I0 + c;
    out[gi2*NN + gj2] = fsigmoid(v2) * nmask[gi2] * nmask[gj2];
}

extern "C" void kernel_launch(void* const* d_in, const int* in_sizes, int n_in,
                              void* d_out, int out_size, void* d_ws, size_t ws_size,
                              hipStream_t stream) {
    const float* pos   = (const float*)d_in[0];
    const float* adjp  = (const float*)d_in[1];
    const float* nmask = (const float*)d_in[2];
    const int*   tp    = (const int*)d_in[3];
    const float* tw1   = (const float*)d_in[4];
    const float* tb1   = (const float*)d_in[5];
    const float* tw2   = (const float*)d_in[6];
    const float* tb2   = (const float*)d_in[7];
    const float* pw    = (const float*)d_in[8];
    const float* pb    = (const float*)d_in[9];
    const float* ew1   = (const float*)d_in[10];
    const float* eb1   = (const float*)d_in[11];
    const float* ew2   = (const float*)d_in[12];
    const float* eb2   = (const float*)d_in[13];
    const float* mw    = (const float*)d_in[14];
    const float* mb    = (const float*)d_in[15];
    const float* aw1   = (const float*)d_in[16];
    const float* ab1   = (const float*)d_in[17];
    const float* aw2   = (const float*)d_in[18];
    const float* ab2   = (const float*)d_in[19];
    const float* hw1   = (const float*)d_in[20];
    const float* hb1   = (const float*)d_in[21];
    const float* hw2   = (const float*)d_in[22];
    const float* hb2   = (const float*)d_in[23];
    float* ws  = (float*)d_ws;
    float* out = (float*)d_out;

    hipLaunchKernelGGL(k_time, dim3(1), dim3(64), 0, stream,
                       tp, tw1, tb1, tw2, tb2, mw, mb, hw1, hb1, ws);
    hipLaunchKernelGGL(k_main, dim3(NN), dim3(256), 0, stream,
                       pos, adjp, nmask, pw, pb, ew1, eb1, ew2, eb2,
                       mw, aw1, hw1, hw2, hb2, ws, out);
    hipLaunchKernelGGL(k_adj, dim3((NN/16)*((NN/16)+1)/2), dim3(256), 0, stream,
                       ws, nmask, ab1, aw2, ab2, out);
}

// Round 5
// 174.936 us; speedup vs baseline: 1.2835x; 1.2835x over previous
//
#include <hip/hip_runtime.h>
#include <math.h>

#define NN 1024
#define HD 64
#define NL 3

// ws layout (floats): hi[N*64] | hj[N*64]
#define WHI 0
#define WHJ (NN*HD)

__device__ __forceinline__ float fsilu(float x) {
    float e = __expf(-x);
    return x * __builtin_amdgcn_rcpf(1.0f + e);
}
__device__ __forceinline__ float fsigmoid(float x) {
    float e = __expf(-x);
    return __builtin_amdgcn_rcpf(1.0f + e);
}

// ---------------- kernel 1: per-row fused everything ----------------------
// One block (512 thr) per row i. Computes time-embedding redundantly per
// block (cheap, L2-broadcast loads), compacts the adj row, runs 3 message-
// passing layers with the N^2xHxH matmul factored OUT of the edge sum
// (msg = (sum_j silu(g_j))@ew2 + deg*eb2 + h), then eps head + adj-head
// row projections.
__global__ __launch_bounds__(512, 6) void k_main(
    const float* __restrict__ pos, const float* __restrict__ adj,
    const float* __restrict__ nmask, const int* __restrict__ tp,
    const float* __restrict__ tw1, const float* __restrict__ tb1,
    const float* __restrict__ tw2, const float* __restrict__ tb2,
    const float* __restrict__ pw, const float* __restrict__ pb,
    const float* __restrict__ ew1, const float* __restrict__ eb1,
    const float* __restrict__ ew2, const float* __restrict__ eb2,
    const float* __restrict__ mw,  const float* __restrict__ mb,
    const float* __restrict__ aw1,
    const float* __restrict__ hw1, const float* __restrict__ hb1,
    const float* __restrict__ hw2, const float* __restrict__ hb2,
    float* __restrict__ ws, float* __restrict__ out)
{
    __shared__ float4 s_ef[NN];       // compacted (dx,dy,dz,dist)   16KB
    __shared__ float  s_red[2048];    // reduction scratch            8KB
    __shared__ float  s_cat[3*HD];    // [h | msg | te]             768B
    __shared__ float  s_s[HD];        // edge-silu sum
    __shared__ float  s_eu[HD];       // eps-head hidden
    __shared__ int    s_nnz;

    const int i = blockIdx.x;
    const int t = threadIdx.x;
    const int lane = t & 63;

    if (t == 0) s_nnz = 0;
    __syncthreads();

    // ---- compact nonzero adj entries + rel/dist (adj is binary 0/1) ----
    const float pix = pos[3*i+0], piy = pos[3*i+1], piz = pos[3*i+2];
    for (int base = 0; base < NN; base += 512) {
        const int j = base + t;
        const bool nz = (adj[i*NN + j] != 0.0f);
        const unsigned long long m = __ballot(nz);
        int wb = 0;
        if (lane == 0) wb = atomicAdd(&s_nnz, __popcll(m));
        wb = __shfl(wb, 0);
        if (nz) {
            const int k = wb + __popcll(m & ((1ull << lane) - 1ull));
            const float dx = pix - pos[3*j+0];
            const float dy = piy - pos[3*j+1];
            const float dz = piz - pos[3*j+2];
            s_ef[k] = make_float4(dx, dy, dz, sqrtf(dx*dx + dy*dy + dz*dz));
        }
    }
    // ---- time embedding (per-block redundant; loads hit L2) ----
    if (t < HD) {
        const float tv = (float)(*tp);
        const float fr = expf((float)(t & 31) * (-logf(10000.0f) / 31.0f));
        const float ang = tv * fr;
        s_red[t] = (t < 32) ? sinf(ang) : cosf(ang);
    }
    __syncthreads();
    const int nnz = s_nnz;
    const float deg = (float)nnz;     // adj values are exactly 0/1
    if (t < HD) {
        float a = tb1[t];
        #pragma unroll 8
        for (int k = 0; k < HD; ++k) a = fmaf(s_red[k], tw1[k*HD + t], a);
        s_red[HD + t] = fsilu(a);
    }
    __syncthreads();
    if (t < HD) {
        float te = tb2[t];
        #pragma unroll 8
        for (int k = 0; k < HD; ++k) te = fmaf(s_red[HD + k], tw2[k*HD + t], te);
        s_cat[2*HD + t] = te;
        // h0 = pos@pw + pb + te
        float a = pb[t] + te;
        a = fmaf(pix, pw[0*HD + t], a);
        a = fmaf(piy, pw[1*HD + t], a);
        a = fmaf(piz, pw[2*HD + t], a);
        s_cat[t] = a;
    }
    __syncthreads();

    const int jj = t >> 4;            // 32 j-groups
    const int hb = (t & 15) << 2;     // 16 h-groups of 4
    const int q  = t >> 6;            // wave id (0..7)
    const int h2 = t & 63;

    for (int l = 0; l < NL; ++l) {
        // loop-invariant edge-MLP weights for this thread's 4 h columns
        float w0[4], w1[4], w2[4], w3[4], bb[4];
        #pragma unroll
        for (int r = 0; r < 4; ++r) {
            w0[r] = ew1[(l*4 + 0)*HD + hb + r];
            w1[r] = ew1[(l*4 + 1)*HD + hb + r];
            w2[r] = ew1[(l*4 + 2)*HD + hb + r];
            w3[r] = ew1[(l*4 + 3)*HD + hb + r];
            bb[r] = eb1[l*HD + hb + r];
        }
        // phase 1: s[h] = sum_{nz j} silu(ef_in @ ew1 + eb1)
        float acc[4] = {0.f, 0.f, 0.f, 0.f};
        for (int k = jj; k < nnz; k += 32) {
            const float4 ef = s_ef[k];
            #pragma unroll
            for (int r = 0; r < 4; ++r) {
                float g = fmaf(ef.x, w0[r], bb[r]);
                g = fmaf(ef.y, w1[r], g);
                g = fmaf(ef.z, w2[r], g);
                g = fmaf(ef.w, w3[r], g);
                acc[r] += fsilu(g);
            }
        }
        *reinterpret_cast<float4*>(&s_red[jj*HD + hb]) =
            make_float4(acc[0], acc[1], acc[2], acc[3]);
        __syncthreads();                                   // S1
        if (t < HD) {
            float s = 0.0f;
            #pragma unroll
            for (int ww = 0; ww < 32; ++ww) s += s_red[ww*HD + t];
            s_s[t] = s;
        }
        __syncthreads();                                   // S2
        // phase 2a: msg = s@ew2 + deg*eb2 + h   (8-wave split over k)
        {
            float pm = 0.0f;
            #pragma unroll
            for (int kk = 0; kk < 8; ++kk) {
                const int k = q*8 + kk;
                pm = fmaf(s_s[k], ew2[(l*HD + k)*HD + h2], pm);
            }
            s_red[q*HD + h2] = pm;
        }
        __syncthreads();                                   // S3
        if (t < HD) {
            float m = 0.0f;
            #pragma unroll
            for (int w = 0; w < 8; ++w) m += s_red[w*HD + t];
            m = fmaf(deg, eb2[l*HD + t], m);
            s_cat[HD + t] = m + s_cat[t];
        }
        __syncthreads();                                   // S4
        // phase 2b: h = silu([h,msg,te]@mw + mb)   (8-wave split over k)
        {
            float ph = 0.0f;
            #pragma unroll
            for (int kk = 0; kk < 24; ++kk) {
                const int row = q*24 + kk;
                ph = fmaf(s_cat[row], mw[(l*3*HD + row)*HD + h2], ph);
            }
            s_red[q*HD + h2] = ph;
        }
        __syncthreads();                                   // S5
        if (t < HD) {
            float a = mb[l*HD + t];
            #pragma unroll
            for (int w = 0; w < 8; ++w) a += s_red[w*HD + t];
            s_cat[t] = fsilu(a);
        }
        __syncthreads();                                   // S6
    }

    // ---- tail: eps head (te folded in) + hi/hj projections ----
    if (t < HD) {
        float a = hb1[t];
        #pragma unroll 8
        for (int k = 0; k < HD; ++k) a = fmaf(s_cat[k], hw1[k*HD + t], a);
        #pragma unroll 8
        for (int k = 0; k < HD; ++k) a = fmaf(s_cat[2*HD + k], hw1[(HD + k)*HD + t], a);
        s_eu[t] = fsilu(a);
    } else if (t < 2*HD) {
        const int c = t - HD;
        float a1 = 0.f, a2 = 0.f;
        #pragma unroll 8
        for (int k = 0; k < HD; ++k) {
            a1 = fmaf(s_cat[k], aw1[k*HD + c], a1);
            a2 = fmaf(s_cat[k], aw1[(HD + k)*HD + c], a2);
        }
        ws[WHI + i*HD + c] = a1;
        ws[WHJ + i*HD + c] = a2;
    }
    __syncthreads();                                       // S7
    if (t < 3) {
        float e = hb2[t];
        for (int k = 0; k < HD; ++k) e = fmaf(s_eu[k], hw2[k*3 + t], e);
        out[NN*NN + i*3 + t] = e * nmask[i];
    }
}

// ---------------- kernel 2: adj head on unordered tile pairs ---------------
__global__ __launch_bounds__(256) void k_adj(
    const float* __restrict__ ws, const float* __restrict__ nmask,
    const float* __restrict__ ab1, const float* __restrict__ aw2,
    const float* __restrict__ ab2, float* __restrict__ out)
{
    __shared__ float4 s_hiI[16*17], s_hjJ[16*17], s_hiJ[16*17], s_hjI[16*17];
    __shared__ float4 s_ab[16], s_w[16];
    __shared__ float s_L1[16][17], s_L2[16][17];
    const int T = NN / 16;  // 64 tiles per side
    const int b = blockIdx.x;
    // decode unordered pair (I <= J) from linear index b
    int I = (int)((2.0*T + 1.0 -
                   sqrt((2.0*T + 1.0)*(2.0*T + 1.0) - 8.0*(double)b)) * 0.5);
    if (I < 0) I = 0; if (I > T-1) I = T-1;
    while (I+1 <= T-1 && ((I+1)*T - ((I+1)*I)/2) <= b) ++I;
    while (I > 0 && (I*T - (I*(I-1))/2) > b) --I;
    const int J = I + (b - (I*T - (I*(I-1))/2));
    const int I0 = I*16, J0 = J*16;
    const int t = threadIdx.x;
    const float* hi = ws + WHI;
    const float* hj = ws + WHJ;
    if (t < 16) { s_ab[t] = ((const float4*)ab1)[t]; s_w[t] = ((const float4*)aw2)[t]; }
    // stage hi/hj rows for both tiles (padded [16][17] float4 -> conflict-free)
    for (int idx = t; idx < 4*16*16; idx += 256) {
        const int arr = idx >> 8, rem = idx & 255, r = rem >> 4, qq = rem & 15;
        const float* src = (arr == 0 || arr == 2) ? hi : hj;
        const int rowt = (arr == 0 || arr == 3) ? I0 : J0;
        const float4 v = *reinterpret_cast<const float4*>(src + (rowt + r)*HD + qq*4);
        float4* dst = (arr == 0) ? s_hiI : (arr == 1) ? s_hjJ
                     : (arr == 2) ? s_hiJ : s_hjI;
        dst[r*17 + qq] = v;
    }
    __syncthreads();
    const int r = t >> 4, c = t & 15;
    float l1 = 0.f, l2 = 0.f;
    #pragma unroll
    for (int hq = 0; hq < 16; ++hq) {
        const float4 aI = s_hiI[r*17 + hq];
        const float4 bJ = s_hjJ[c*17 + hq];
        const float4 aJ = s_hiJ[r*17 + hq];
        const float4 bI = s_hjI[c*17 + hq];
        const float4 ab = s_ab[hq];
        const float4 w  = s_w[hq];
        l1 += fsilu(aI.x + bJ.x + ab.x)*w.x + fsilu(aI.y + bJ.y + ab.y)*w.y
            + fsilu(aI.z + bJ.z + ab.z)*w.z + fsilu(aI.w + bJ.w + ab.w)*w.w;
        l2 += fsilu(aJ.x + bI.x + ab.x)*w.x + fsilu(aJ.y + bI.y + ab.y)*w.y
            + fsilu(aJ.z + bI.z + ab.z)*w.z + fsilu(aJ.w + bI.w + ab.w)*w.w;
    }
    const float b2 = ab2[0];
    s_L1[r][c] = l1 + b2;   // logits(I0+r, J0+c)
    s_L2[r][c] = l2 + b2;   // logits(J0+r, I0+c)
    __syncthreads();
    const float v1 = 0.5f*(s_L1[r][c] + s_L2[c][r]);
    const float v2 = 0.5f*(s_L2[r][c] + s_L1[c][r]);
    const int gi1 = I0 + r, gj1 = J0 + c;
    out[gi1*NN + gj1] = fsigmoid(v1) * nmask[gi1] * nmask[gj1];
    const int gi2 = J0 + r, gj2 = I0 + c;
    out[gi2*NN + gj2] = fsigmoid(v2) * nmask[gi2] * nmask[gj2];
}

extern "C" void kernel_launch(void* const* d_in, const int* in_sizes, int n_in,
                              void* d_out, int out_size, void* d_ws, size_t ws_size,
                              hipStream_t stream) {
    const float* pos   = (const float*)d_in[0];
    const float* adjp  = (const float*)d_in[1];
    const float* nmask = (const float*)d_in[2];
    const int*   tp    = (const int*)d_in[3];
    const float* tw1   = (const float*)d_in[4];
    const float* tb1   = (const float*)d_in[5];
    const float* tw2   = (const float*)d_in[6];
    const float* tb2   = (const float*)d_in[7];
    const float* pw    = (const float*)d_in[8];
    const float* pb    = (const float*)d_in[9];
    const float* ew1   = (const float*)d_in[10];
    const float* eb1   = (const float*)d_in[11];
    const float* ew2   = (const float*)d_in[12];
    const float* eb2   = (const float*)d_in[13];
    const float* mw    = (const float*)d_in[14];
    const float* mb    = (const float*)d_in[15];
    const float* aw1   = (const float*)d_in[16];
    const float* ab1   = (const float*)d_in[17];
    const float* aw2   = (const float*)d_in[18];
    const float* ab2   = (const float*)d_in[19];
    const float* hw1   = (const float*)d_in[20];
    const float* hb1   = (const float*)d_in[21];
    const float* hw2   = (const float*)d_in[22];
    const float* hb2   = (const float*)d_in[23];
    float* ws  = (float*)d_ws;
    float* out = (float*)d_out;

    hipLaunchKernelGGL(k_main, dim3(NN), dim3(512), 0, stream,
                       pos, adjp, nmask, tp, tw1, tb1, tw2, tb2, pw, pb,
                       ew1, eb1, ew2, eb2, mw, mb, aw1, hw1, hb1, hw2, hb2,
                       ws, out);
    hipLaunchKernelGGL(k_adj, dim3((NN/16)*((NN/16)+1)/2), dim3(256), 0, stream,
                       ws, nmask, ab1, aw2, ab2, out);
}

// Round 10
// 166.398 us; speedup vs baseline: 1.3494x; 1.0513x over previous
//
#include <hip/hip_runtime.h>
#include <math.h>

#define NN 1024
#define HD 64
#define NL 3

// ws layout (floats):
#define WTE 0                     // te[64]
#define WTC 64                    // tc[3][64]  = mb + te@mw_t
#define WEC 256                   // ec[64]     = hb1 + te@hw1_te
#define WCV 320                   // c[3][64]   = eb2@mw_m
#define WW  512                   // W[3][128][64]: rows 0-63 = mw_h+mw_m, 64-127 = ew2@mw_m
#define WHI (512 + 3*128*64)      // hi[N][64]
#define WHJ (WHI + NN*HD)         // hj[N][64] (pre-biased with ab1)

__device__ __forceinline__ float fsilu(float x) {
    float e = __expf(-x);
    return x * __builtin_amdgcn_rcpf(1.0f + e);
}
__device__ __forceinline__ float fsigmoid(float x) {
    float e = __expf(-x);
    return __builtin_amdgcn_rcpf(1.0f + e);
}

// -------- kernel 0: precompute folded weights + time-embedding tables ------
// Algebra: h' = silu([h,msg,te]@mw + mb), msg = s@ew2 + deg*eb2 + h
//   =>  h' = silu( h@(mw_h+mw_m) + s@(ew2@mw_m) + deg*(eb2@mw_m) + mb+te@mw_t )
__global__ __launch_bounds__(256) void k_pre(
    const int* __restrict__ tp,
    const float* __restrict__ tw1, const float* __restrict__ tb1,
    const float* __restrict__ tw2, const float* __restrict__ tb2,
    const float* __restrict__ ew2, const float* __restrict__ eb2,
    const float* __restrict__ mw,  const float* __restrict__ mb,
    const float* __restrict__ hw1, const float* __restrict__ hb1,
    float* __restrict__ ws)
{
    const int b = blockIdx.x, t = threadIdx.x;
    if (b == 0) {
        __shared__ float raw[HD], x1[HD], te[HD];
        if (t < HD) {
            const float tv = (float)(*tp);
            const float fr = __expf((float)(t & 31) * (-logf(10000.0f) / 31.0f));
            const float ang = tv * fr;
            raw[t] = (t < 32) ? sinf(ang) : cosf(ang);
        }
        __syncthreads();
        if (t < HD) {
            float a = tb1[t];
            #pragma unroll 8
            for (int k = 0; k < HD; ++k) a = fmaf(raw[k], tw1[k*HD + t], a);
            x1[t] = fsilu(a);
        }
        __syncthreads();
        if (t < HD) {
            float a = tb2[t];
            #pragma unroll 8
            for (int k = 0; k < HD; ++k) a = fmaf(x1[k], tw2[k*HD + t], a);
            te[t] = a;
            ws[WTE + t] = a;
        }
        __syncthreads();
        if (t < 192) {
            const int l = t >> 6, h = t & 63;
            float a = mb[l*HD + h];          // tc = mb + te@mw_t
            float c = 0.0f;                  // c  = eb2@mw_m
            #pragma unroll 8
            for (int k = 0; k < HD; ++k) {
                a = fmaf(te[k],          mw[(l*3*HD + 2*HD + k)*HD + h], a);
                c = fmaf(eb2[l*HD + k],  mw[(l*3*HD +   HD + k)*HD + h], c);
            }
            ws[WTC + t] = a;
            ws[WCV + t] = c;
        } else {
            const int h = t - 192;           // ec = hb1 + te@hw1_te
            float a = hb1[h];
            #pragma unroll 8
            for (int k = 0; k < HD; ++k) a = fmaf(te[k], hw1[(HD + k)*HD + h], a);
            ws[WEC + h] = a;
        }
    } else {
        const int l = b - 1;
        __shared__ float s_w2[HD*HD];   // ew2[l]
        __shared__ float s_mm[HD*HD];   // mw_m[l]
        for (int o = t; o < HD*HD; o += 256) {
            const int r = o >> 6, h = o & 63;
            s_w2[o] = ew2[l*HD*HD + o];
            const float mm = mw[(l*3*HD + HD + r)*HD + h];
            s_mm[o] = mm;
            // A = mw_h + mw_m  (rows 0-63 of W_l)
            ws[WW + l*128*HD + o] = mw[(l*3*HD + r)*HD + h] + mm;
        }
        __syncthreads();
        // E = ew2 @ mw_m  (rows 64-127 of W_l)
        const int h = t & 63, r0 = t >> 6;   // each thread: 16 rows, one col
        float acc[16];
        #pragma unroll
        for (int ri = 0; ri < 16; ++ri) acc[ri] = 0.0f;
        for (int k = 0; k < HD; ++k) {
            const float mv = s_mm[k*HD + h];
            #pragma unroll
            for (int ri = 0; ri < 16; ++ri)
                acc[ri] = fmaf(s_w2[(r0*16 + ri)*HD + k], mv, acc[ri]);
        }
        #pragma unroll
        for (int ri = 0; ri < 16; ++ri)
            ws[WW + l*128*HD + (HD + r0*16 + ri)*HD + h] = acc[ri];
    }
}

// -------- kernel 1: per-row fused 3-layer message passing ------------------
__global__ __launch_bounds__(512, 6) void k_main(
    const float* __restrict__ pos, const float* __restrict__ adj,
    const float* __restrict__ nmask,
    const float* __restrict__ pw, const float* __restrict__ pb,
    const float* __restrict__ ew1, const float* __restrict__ eb1,
    const float* __restrict__ aw1, const float* __restrict__ ab1,
    const float* __restrict__ hw1,
    const float* __restrict__ hw2, const float* __restrict__ hb2,
    float* __restrict__ ws, float* __restrict__ out)
{
    __shared__ float4 s_ef[NN];          // compacted (dx,dy,dz,dist)  16KB
    __shared__ float  s_red[16*NL*HD];   // phase-1 partials / reuse   12KB
    __shared__ float  s_s[NL*HD];        // the 3 geometry sums
    __shared__ float  s_h[HD], s_eu[HD];
    __shared__ int    s_nnz;

    const int i = blockIdx.x;
    const int t = threadIdx.x;
    const int lane = t & 63;

    if (t == 0) s_nnz = 0;
    __syncthreads();

    // ---- compact nonzero adj entries + rel/dist (adj is binary 0/1) ----
    const float pix = pos[3*i+0], piy = pos[3*i+1], piz = pos[3*i+2];
    for (int base = 0; base < NN; base += 512) {
        const int j = base + t;
        const bool nz = (adj[i*NN + j] != 0.0f);
        const unsigned long long m = __ballot(nz);
        int wb = 0;
        if (lane == 0) wb = atomicAdd(&s_nnz, __popcll(m));
        wb = __shfl(wb, 0);
        if (nz) {
            const int k = wb + __popcll(m & ((1ull << lane) - 1ull));
            const float dx = pix - pos[3*j+0];
            const float dy = piy - pos[3*j+1];
            const float dz = piz - pos[3*j+2];
            s_ef[k] = make_float4(dx, dy, dz, sqrtf(dx*dx + dy*dy + dz*dz));
        }
    }
    if (t < HD) {   // h0 = pos@pw + pb + te
        float a = pb[t] + ws[WTE + t];
        a = fmaf(pix, pw[0*HD + t], a);
        a = fmaf(piy, pw[1*HD + t], a);
        a = fmaf(piz, pw[2*HD + t], a);
        s_h[t] = a;
    }
    __syncthreads();
    const int nnz = s_nnz;
    const float deg = (float)nnz;        // adj values are exactly 0/1

    // ---- phase 1 (ALL 3 layers, h-independent, barrier-free single pass):
    //      s_l[h] = sum_{nz j} silu(ef_j @ ew1[l] + eb1[l])
    const int jj = t >> 5;               // 16 j-groups
    const int hp = t & 31;               // cols hp and hp+32
    float w[NL][2][4], bb[NL][2], acc[NL][2];
    #pragma unroll
    for (int l = 0; l < NL; ++l)
        #pragma unroll
        for (int c = 0; c < 2; ++c) {
            const int hc = hp + 32*c;
            #pragma unroll
            for (int m = 0; m < 4; ++m) w[l][c][m] = ew1[(l*4 + m)*HD + hc];
            bb[l][c] = eb1[l*HD + hc];
            acc[l][c] = 0.0f;
        }
    for (int k = jj; k < nnz; k += 16) {
        const float4 ef = s_ef[k];
        #pragma unroll
        for (int l = 0; l < NL; ++l)
            #pragma unroll
            for (int c = 0; c < 2; ++c) {
                float g = fmaf(ef.x, w[l][c][0], bb[l][c]);
                g = fmaf(ef.y, w[l][c][1], g);
                g = fmaf(ef.z, w[l][c][2], g);
                g = fmaf(ef.w, w[l][c][3], g);
                acc[l][c] += fsilu(g);
            }
    }
    #pragma unroll
    for (int l = 0; l < NL; ++l)
        #pragma unroll
        for (int c = 0; c < 2; ++c)
            s_red[(l*16 + jj)*HD + hp + 32*c] = acc[l][c];
    __syncthreads();
    if (t < NL*HD) {
        const int l = t >> 6, h = t & 63;
        float s = 0.0f;
        #pragma unroll
        for (int g = 0; g < 16; ++g) s += s_red[(l*16 + g)*HD + h];
        s_s[l*HD + h] = s;
    }
    __syncthreads();

    // ---- phase 2: h' = silu( [h|s_l] @ W_l + deg*c_l + tc_l ) ------------
    const int q = t >> 6, h2 = t & 63;
    for (int l = 0; l < NL; ++l) {
        const float* Wl = ws + WW + l*128*HD;
        float pm = 0.0f;
        #pragma unroll
        for (int kk = 0; kk < 16; ++kk) {
            const int row = q*16 + kk;
            const float x = (row < HD) ? s_h[row] : s_s[l*HD + row - HD];
            pm = fmaf(x, Wl[row*HD + h2], pm);
        }
        s_red[q*HD + h2] = pm;
        __syncthreads();
        if (t < HD) {
            float a = ws[WTC + l*HD + t];
            a = fmaf(deg, ws[WCV + l*HD + t], a);
            #pragma unroll
            for (int g = 0; g < 8; ++g) a += s_red[g*HD + t];
            s_h[t] = fsilu(a);
        }
        __syncthreads();
    }

    // ---- tail: eps-head hidden + adj-head projections (3 parallel matvecs)
    if (t < 192) {
        const int sel = t >> 6, col = t & 63;
        if (sel == 0) {
            float a = ws[WEC + col];
            #pragma unroll 8
            for (int k = 0; k < HD; ++k) a = fmaf(s_h[k], hw1[k*HD + col], a);
            s_eu[col] = fsilu(a);
        } else if (sel == 1) {
            float a = 0.0f;
            #pragma unroll 8
            for (int k = 0; k < HD; ++k) a = fmaf(s_h[k], aw1[k*HD + col], a);
            ws[WHI + i*HD + col] = a;
        } else {
            float a = ab1[col];   // fold ab1 into hj
            #pragma unroll 8
            for (int k = 0; k < HD; ++k) a = fmaf(s_h[k], aw1[(HD + k)*HD + col], a);
            ws[WHJ + i*HD + col] = a;
        }
    }
    __syncthreads();
    if (t < 3) {
        float e = hb2[t];
        for (int k = 0; k < HD; ++k) e = fmaf(s_eu[k], hw2[k*3 + t], e);
        out[NN*NN + i*3 + t] = e * nmask[i];
    }
}

// -------- kernel 2: adj head on unordered tile pairs -----------------------
__global__ __launch_bounds__(256) void k_adj(
    const float* __restrict__ ws, const float* __restrict__ nmask,
    const float* __restrict__ aw2, const float* __restrict__ ab2,
    float* __restrict__ out)
{
    __shared__ float4 s_hiI[16*17], s_hjJ[16*17], s_hiJ[16*17], s_hjI[16*17];
    __shared__ float4 s_w[16];
    __shared__ float s_L1[16][17], s_L2[16][17];
    const int T = NN / 16;  // 64 tiles per side
    const int b = blockIdx.x;
    // decode unordered pair (I <= J) from linear index b
    int I = (int)((2.0*T + 1.0 -
                   sqrt((2.0*T + 1.0)*(2.0*T + 1.0) - 8.0*(double)b)) * 0.5);
    if (I < 0) I = 0; if (I > T-1) I = T-1;
    while (I+1 <= T-1 && ((I+1)*T - ((I+1)*I)/2) <= b) ++I;
    while (I > 0 && (I*T - (I*(I-1))/2) > b) --I;
    const int J = I + (b - (I*T - (I*(I-1))/2));
    const int I0 = I*16, J0 = J*16;
    const int t = threadIdx.x;
    const float* hi = ws + WHI;
    const float* hj = ws + WHJ;   // pre-biased with ab1
    if (t < 16) s_w[t] = ((const float4*)aw2)[t];
    // stage hi/hj rows for both tiles (padded [16][17] float4 -> conflict-free)
    for (int idx = t; idx < 4*16*16; idx += 256) {
        const int arr = idx >> 8, rem = idx & 255, r = rem >> 4, qq = rem & 15;
        const float* src = (arr == 0 || arr == 2) ? hi : hj;
        const int rowt = (arr == 0 || arr == 3) ? I0 : J0;
        const float4 v = *reinterpret_cast<const float4*>(src + (rowt + r)*HD + qq*4);
        float4* dst = (arr == 0) ? s_hiI : (arr == 1) ? s_hjJ
                     : (arr == 2) ? s_hiJ : s_hjI;
        dst[r*17 + qq] = v;
    }
    __syncthreads();
    const int r = t >> 4, c = t & 15;
    float l1 = 0.f, l2 = 0.f;
    #pragma unroll
    for (int hq = 0; hq < 16; ++hq) {
        const float4 aI = s_hiI[r*17 + hq];
        const float4 bJ = s_hjJ[c*17 + hq];
        const float4 aJ = s_hiJ[r*17 + hq];
        const float4 bI = s_hjI[c*17 + hq];
        const float4 w  = s_w[hq];
        l1 += fsilu(aI.x + bJ.x)*w.x + fsilu(aI.y + bJ.y)*w.y
            + fsilu(aI.z + bJ.z)*w.z + fsilu(aI.w + bJ.w)*w.w;
        l2 += fsilu(aJ.x + bI.x)*w.x + fsilu(aJ.y + bI.y)*w.y
            + fsilu(aJ.z + bI.z)*w.z + fsilu(aJ.w + bI.w)*w.w;
    }
    const float b2 = ab2[0];
    s_L1[r][c] = l1 + b2;   // logits(I0+r, J0+c)
    s_L2[r][c] = l2 + b2;   // logits(J0+r, I0+c)
    __syncthreads();
    const float v1 = 0.5f*(s_L1[r][c] + s_L2[c][r]);
    const float v2 = 0.5f*(s_L2[r][c] + s_L1[c][r]);
    const int gi1 = I0 + r, gj1 = J0 + c;
    out[gi1*NN + gj1] = fsigmoid(v1) * nmask[gi1] * nmask[gj1];
    const int gi2 = J0 + r, gj2 = I0 + c;
    out[gi2*NN + gj2] = fsigmoid(v2) * nmask[gi2] * nmask[gj2];
}

extern "C" void kernel_launch(void* const* d_in, const int* in_sizes, int n_in,
                              void* d_out, int out_size, void* d_ws, size_t ws_size,
                              hipStream_t stream) {
    const float* pos   = (const float*)d_in[0];
    const float* adjp  = (const float*)d_in[1];
    const float* nmask = (const float*)d_in[2];
    const int*   tp    = (const int*)d_in[3];
    const float* tw1   = (const float*)d_in[4];
    const float* tb1   = (const float*)d_in[5];
    const float* tw2   = (const float*)d_in[6];
    const float* tb2   = (const float*)d_in[7];
    const float* pw    = (const float*)d_in[8];
    const float* pb    = (const float*)d_in[9];
    const float* ew1   = (const float*)d_in[10];
    const float* eb1   = (const float*)d_in[11];
    const float* ew2   = (const float*)d_in[12];
    const float* eb2   = (const float*)d_in[13];
    const float* mw    = (const float*)d_in[14];
    const float* mb    = (const float*)d_in[15];
    const float* aw1   = (const float*)d_in[16];
    const float* ab1   = (const float*)d_in[17];
    const float* aw2   = (const float*)d_in[18];
    const float* ab2   = (const float*)d_in[19];
    const float* hw1   = (const float*)d_in[20];
    const float* hb1   = (const float*)d_in[21];
    const float* hw2   = (const float*)d_in[22];
    const float* hb2   = (const float*)d_in[23];
    float* ws  = (float*)d_ws;
    float* out = (float*)d_out;

    hipLaunchKernelGGL(k_pre, dim3(1 + NL), dim3(256), 0, stream,
                       tp, tw1, tb1, tw2, tb2, ew2, eb2, mw, mb, hw1, hb1, ws);
    hipLaunchKernelGGL(k_main, dim3(NN), dim3(512), 0, stream,
                       pos, adjp, nmask, pw, pb, ew1, eb1, aw1, ab1,
                       hw1, hw2, hb2, ws, out);
    hipLaunchKernelGGL(k_adj, dim3((NN/16)*((NN/16)+1)/2), dim3(256), 0, stream,
                       ws, nmask, aw2, ab2, out);
}

// Round 11
// 165.745 us; speedup vs baseline: 1.3547x; 1.0039x over previous
//
#include <hip/hip_runtime.h>
#include <math.h>

#define NN 1024
#define HD 64
#define NL 3

// ws layout (floats):
#define WTE 0                     // te[64]
#define WTC 64                    // tc[3][64]  = mb + te@mw_t
#define WEC 256                   // ec[64]     = hb1 + te@hw1_te
#define WCV 320                   // c[3][64]   = eb2@mw_m
#define WW  512                   // W[3][128][64]: rows 0-63 = mw_h+mw_m, 64-127 = ew2@mw_m
#define WHI (512 + 3*128*64)      // hi[N][64]
#define WHJ (WHI + NN*HD)         // hj[N][64] (pre-biased with ab1)

__device__ __forceinline__ float fsilu(float x) {
    float e = __expf(-x);
    return x * __builtin_amdgcn_rcpf(1.0f + e);
}
__device__ __forceinline__ float fsigmoid(float x) {
    float e = __expf(-x);
    return __builtin_amdgcn_rcpf(1.0f + e);
}

// -------- kernel 0: precompute folded weights + time-embedding tables ------
// Algebra: h' = silu([h,msg,te]@mw + mb), msg = s@ew2 + deg*eb2 + h
//   =>  h' = silu( h@(mw_h+mw_m) + s@(ew2@mw_m) + deg*(eb2@mw_m) + mb+te@mw_t )
__global__ __launch_bounds__(256) void k_pre(
    const int* __restrict__ tp,
    const float* __restrict__ tw1, const float* __restrict__ tb1,
    const float* __restrict__ tw2, const float* __restrict__ tb2,
    const float* __restrict__ ew2, const float* __restrict__ eb2,
    const float* __restrict__ mw,  const float* __restrict__ mb,
    const float* __restrict__ hw1, const float* __restrict__ hb1,
    float* __restrict__ ws)
{
    const int b = blockIdx.x, t = threadIdx.x;
    if (b == 0) {
        __shared__ float raw[HD], x1[HD], te[HD];
        if (t < HD) {
            const float tv = (float)(*tp);
            const float fr = __expf((float)(t & 31) * (-logf(10000.0f) / 31.0f));
            const float ang = tv * fr;
            raw[t] = (t < 32) ? sinf(ang) : cosf(ang);
        }
        __syncthreads();
        if (t < HD) {
            float a = tb1[t];
            #pragma unroll 8
            for (int k = 0; k < HD; ++k) a = fmaf(raw[k], tw1[k*HD + t], a);
            x1[t] = fsilu(a);
        }
        __syncthreads();
        if (t < HD) {
            float a = tb2[t];
            #pragma unroll 8
            for (int k = 0; k < HD; ++k) a = fmaf(x1[k], tw2[k*HD + t], a);
            te[t] = a;
            ws[WTE + t] = a;
        }
        __syncthreads();
        if (t < 192) {
            const int l = t >> 6, h = t & 63;
            float a = mb[l*HD + h];          // tc = mb + te@mw_t
            float c = 0.0f;                  // c  = eb2@mw_m
            #pragma unroll 8
            for (int k = 0; k < HD; ++k) {
                a = fmaf(te[k],          mw[(l*3*HD + 2*HD + k)*HD + h], a);
                c = fmaf(eb2[l*HD + k],  mw[(l*3*HD +   HD + k)*HD + h], c);
            }
            ws[WTC + t] = a;
            ws[WCV + t] = c;
        } else {
            const int h = t - 192;           // ec = hb1 + te@hw1_te
            float a = hb1[h];
            #pragma unroll 8
            for (int k = 0; k < HD; ++k) a = fmaf(te[k], hw1[(HD + k)*HD + h], a);
            ws[WEC + h] = a;
        }
    } else {
        const int l = b - 1;
        __shared__ float s_w2[HD*HD];   // ew2[l]
        __shared__ float s_mm[HD*HD];   // mw_m[l]
        for (int o = t; o < HD*HD; o += 256) {
            const int r = o >> 6, h = o & 63;
            s_w2[o] = ew2[l*HD*HD + o];
            const float mm = mw[(l*3*HD + HD + r)*HD + h];
            s_mm[o] = mm;
            // A = mw_h + mw_m  (rows 0-63 of W_l)
            ws[WW + l*128*HD + o] = mw[(l*3*HD + r)*HD + h] + mm;
        }
        __syncthreads();
        // E = ew2 @ mw_m  (rows 64-127 of W_l)
        const int h = t & 63, r0 = t >> 6;   // each thread: 16 rows, one col
        float acc[16];
        #pragma unroll
        for (int ri = 0; ri < 16; ++ri) acc[ri] = 0.0f;
        for (int k = 0; k < HD; ++k) {
            const float mv = s_mm[k*HD + h];
            #pragma unroll
            for (int ri = 0; ri < 16; ++ri)
                acc[ri] = fmaf(s_w2[(r0*16 + ri)*HD + k], mv, acc[ri]);
        }
        #pragma unroll
        for (int ri = 0; ri < 16; ++ri)
            ws[WW + l*128*HD + (HD + r0*16 + ri)*HD + h] = acc[ri];
    }
}

// -------- kernel 1: per-row fused 3-layer message passing ------------------
// (512,8): 4 blocks/CU -> 1024 block-slots == grid -> single occupancy round
__global__ __launch_bounds__(512, 8) void k_main(
    const float* __restrict__ pos, const float* __restrict__ adj,
    const float* __restrict__ nmask,
    const float* __restrict__ pw, const float* __restrict__ pb,
    const float* __restrict__ ew1, const float* __restrict__ eb1,
    const float* __restrict__ aw1, const float* __restrict__ ab1,
    const float* __restrict__ hw1,
    const float* __restrict__ hw2, const float* __restrict__ hb2,
    float* __restrict__ ws, float* __restrict__ out)
{
    __shared__ float4 s_ef[NN];          // compacted (dx,dy,dz,dist)  16KB
    __shared__ float  s_red[16*NL*HD];   // phase-1 partials / reuse   12KB
    __shared__ float  s_s[NL*HD];        // the 3 geometry sums
    __shared__ float  s_h[HD], s_eu[HD];
    __shared__ int    s_nnz;

    const int i = blockIdx.x;
    const int t = threadIdx.x;
    const int lane = t & 63;

    if (t == 0) s_nnz = 0;
    __syncthreads();

    // ---- compact nonzero adj entries + rel/dist (adj is binary 0/1) ----
    const float pix = pos[3*i+0], piy = pos[3*i+1], piz = pos[3*i+2];
    for (int base = 0; base < NN; base += 512) {
        const int j = base + t;
        const bool nz = (adj[i*NN + j] != 0.0f);
        const unsigned long long m = __ballot(nz);
        int wb = 0;
        if (lane == 0) wb = atomicAdd(&s_nnz, __popcll(m));
        wb = __shfl(wb, 0);
        if (nz) {
            const int k = wb + __popcll(m & ((1ull << lane) - 1ull));
            const float dx = pix - pos[3*j+0];
            const float dy = piy - pos[3*j+1];
            const float dz = piz - pos[3*j+2];
            s_ef[k] = make_float4(dx, dy, dz, sqrtf(dx*dx + dy*dy + dz*dz));
        }
    }
    if (t < HD) {   // h0 = pos@pw + pb + te
        float a = pb[t] + ws[WTE + t];
        a = fmaf(pix, pw[0*HD + t], a);
        a = fmaf(piy, pw[1*HD + t], a);
        a = fmaf(piz, pw[2*HD + t], a);
        s_h[t] = a;
    }
    __syncthreads();
    const int nnz = s_nnz;
    const float deg = (float)nnz;        // adj values are exactly 0/1

    // ---- phase 1 (ALL 3 layers, h-independent, barrier-free single pass):
    //      s_l[h] = sum_{nz j} silu(ef_j @ ew1[l] + eb1[l])
    const int jj = t >> 5;               // 16 j-groups
    const int hp = t & 31;               // cols hp and hp+32
    float w[NL][2][4], bb[NL][2], acc[NL][2];
    #pragma unroll
    for (int l = 0; l < NL; ++l)
        #pragma unroll
        for (int c = 0; c < 2; ++c) {
            const int hc = hp + 32*c;
            #pragma unroll
            for (int m = 0; m < 4; ++m) w[l][c][m] = ew1[(l*4 + m)*HD + hc];
            bb[l][c] = eb1[l*HD + hc];
            acc[l][c] = 0.0f;
        }
    for (int k = jj; k < nnz; k += 16) {
        const float4 ef = s_ef[k];
        #pragma unroll
        for (int l = 0; l < NL; ++l)
            #pragma unroll
            for (int c = 0; c < 2; ++c) {
                float g = fmaf(ef.x, w[l][c][0], bb[l][c]);
                g = fmaf(ef.y, w[l][c][1], g);
                g = fmaf(ef.z, w[l][c][2], g);
                g = fmaf(ef.w, w[l][c][3], g);
                acc[l][c] += fsilu(g);
            }
    }
    #pragma unroll
    for (int l = 0; l < NL; ++l)
        #pragma unroll
        for (int c = 0; c < 2; ++c)
            s_red[(l*16 + jj)*HD + hp + 32*c] = acc[l][c];
    __syncthreads();
    if (t < NL*HD) {
        const int l = t >> 6, h = t & 63;
        float s = 0.0f;
        #pragma unroll
        for (int g = 0; g < 16; ++g) s += s_red[(l*16 + g)*HD + h];
        s_s[l*HD + h] = s;
    }
    __syncthreads();

    // ---- phase 2: h' = silu( [h|s_l] @ W_l + deg*c_l + tc_l ) ------------
    const int q = t >> 6, h2 = t & 63;
    for (int l = 0; l < NL; ++l) {
        const float* Wl = ws + WW + l*128*HD;
        float pm = 0.0f;
        #pragma unroll
        for (int kk = 0; kk < 16; ++kk) {
            const int row = q*16 + kk;
            const float x = (row < HD) ? s_h[row] : s_s[l*HD + row - HD];
            pm = fmaf(x, Wl[row*HD + h2], pm);
        }
        s_red[q*HD + h2] = pm;
        __syncthreads();
        if (t < HD) {
            float a = ws[WTC + l*HD + t];
            a = fmaf(deg, ws[WCV + l*HD + t], a);
            #pragma unroll
            for (int g = 0; g < 8; ++g) a += s_red[g*HD + t];
            s_h[t] = fsilu(a);
        }
        __syncthreads();
    }

    // ---- tail: eps-head hidden + adj-head projections (3 parallel matvecs)
    if (t < 192) {
        const int sel = t >> 6, col = t & 63;
        if (sel == 0) {
            float a = ws[WEC + col];
            #pragma unroll 8
            for (int k = 0; k < HD; ++k) a = fmaf(s_h[k], hw1[k*HD + col], a);
            s_eu[col] = fsilu(a);
        } else if (sel == 1) {
            float a = 0.0f;
            #pragma unroll 8
            for (int k = 0; k < HD; ++k) a = fmaf(s_h[k], aw1[k*HD + col], a);
            ws[WHI + i*HD + col] = a;
        } else {
            float a = ab1[col];   // fold ab1 into hj
            #pragma unroll 8
            for (int k = 0; k < HD; ++k) a = fmaf(s_h[k], aw1[(HD + k)*HD + col], a);
            ws[WHJ + i*HD + col] = a;
        }
    }
    __syncthreads();
    if (t < 3) {
        float e = hb2[t];
        for (int k = 0; k < HD; ++k) e = fmaf(s_eu[k], hw2[k*3 + t], e);
        out[NN*NN + i*3 + t] = e * nmask[i];
    }
}

// -------- kernel 2: adj head on unordered tile pairs -----------------------
// (256,8): 8 blocks/CU (LDS 19.6KB x8 = 157KB) -> 2048 slots for 2080 blocks
__global__ __launch_bounds__(256, 8) void k_adj(
    const float* __restrict__ ws, const float* __restrict__ nmask,
    const float* __restrict__ aw2, const float* __restrict__ ab2,
    float* __restrict__ out)
{
    __shared__ float4 s_hiI[16*17], s_hjJ[16*17], s_hiJ[16*17], s_hjI[16*17];
    __shared__ float4 s_w[16];
    __shared__ float s_L1[16][17], s_L2[16][17];
    const int T = NN / 16;  // 64 tiles per side
    const int b = blockIdx.x;
    // decode unordered pair (I <= J) from linear index b
    int I = (int)((2.0*T + 1.0 -
                   sqrt((2.0*T + 1.0)*(2.0*T + 1.0) - 8.0*(double)b)) * 0.5);
    if (I < 0) I = 0; if (I > T-1) I = T-1;
    while (I+1 <= T-1 && ((I+1)*T - ((I+1)*I)/2) <= b) ++I;
    while (I > 0 && (I*T - (I*(I-1))/2) > b) --I;
    const int J = I + (b - (I*T - (I*(I-1))/2));
    const int I0 = I*16, J0 = J*16;
    const int t = threadIdx.x;
    const float* hi = ws + WHI;
    const float* hj = ws + WHJ;   // pre-biased with ab1
    if (t < 16) s_w[t] = ((const float4*)aw2)[t];
    // stage hi/hj rows for both tiles (padded [16][17] float4 -> conflict-free)
    for (int idx = t; idx < 4*16*16; idx += 256) {
        const int arr = idx >> 8, rem = idx & 255, r = rem >> 4, qq = rem & 15;
        const float* src = (arr == 0 || arr == 2) ? hi : hj;
        const int rowt = (arr == 0 || arr == 3) ? I0 : J0;
        const float4 v = *reinterpret_cast<const float4*>(src + (rowt + r)*HD + qq*4);
        float4* dst = (arr == 0) ? s_hiI : (arr == 1) ? s_hjJ
                     : (arr == 2) ? s_hiJ : s_hjI;
        dst[r*17 + qq] = v;
    }
    __syncthreads();
    const int r = t >> 4, c = t & 15;
    float l1 = 0.f, l2 = 0.f;
    #pragma unroll
    for (int hq = 0; hq < 16; ++hq) {
        const float4 aI = s_hiI[r*17 + hq];
        const float4 bJ = s_hjJ[c*17 + hq];
        const float4 aJ = s_hiJ[r*17 + hq];
        const float4 bI = s_hjI[c*17 + hq];
        const float4 w  = s_w[hq];
        l1 += fsilu(aI.x + bJ.x)*w.x + fsilu(aI.y + bJ.y)*w.y
            + fsilu(aI.z + bJ.z)*w.z + fsilu(aI.w + bJ.w)*w.w;
        l2 += fsilu(aJ.x + bI.x)*w.x + fsilu(aJ.y + bI.y)*w.y
            + fsilu(aJ.z + bI.z)*w.z + fsilu(aJ.w + bI.w)*w.w;
    }
    const float b2 = ab2[0];
    s_L1[r][c] = l1 + b2;   // logits(I0+r, J0+c)
    s_L2[r][c] = l2 + b2;   // logits(J0+r, I0+c)
    __syncthreads();
    const float v1 = 0.5f*(s_L1[r][c] + s_L2[c][r]);
    const float v2 = 0.5f*(s_L2[r][c] + s_L1[c][r]);
    const int gi1 = I0 + r, gj1 = J0 + c;
    out[gi1*NN + gj1] = fsigmoid(v1) * nmask[gi1] * nmask[gj1];
    const int gi2 = J0 + r, gj2 = I0 + c;
    out[gi2*NN + gj2] = fsigmoid(v2) * nmask[gi2] * nmask[gj2];
}

extern "C" void kernel_launch(void* const* d_in, const int* in_sizes, int n_in,
                              void* d_out, int out_size, void* d_ws, size_t ws_size,
                              hipStream_t stream) {
    const float* pos   = (const float*)d_in[0];
    const float* adjp  = (const float*)d_in[1];
    const float* nmask = (const float*)d_in[2];
    const int*   tp    = (const int*)d_in[3];
    const float* tw1   = (const float*)d_in[4];
    const float* tb1   = (const float*)d_in[5];
    const float* tw2   = (const float*)d_in[6];
    const float* tb2   = (const float*)d_in[7];
    const float* pw    = (const float*)d_in[8];
    const float* pb    = (const float*)d_in[9];
    const float* ew1   = (const float*)d_in[10];
    const float* eb1   = (const float*)d_in[11];
    const float* ew2   = (const float*)d_in[12];
    const float* eb2   = (const float*)d_in[13];
    const float* mw    = (const float*)d_in[14];
    const float* mb    = (const float*)d_in[15];
    const float* aw1   = (const float*)d_in[16];
    const float* ab1   = (const float*)d_in[17];
    const float* aw2   = (const float*)d_in[18];
    const float* ab2   = (const float*)d_in[19];
    const float* hw1   = (const float*)d_in[20];
    const float* hb1   = (const float*)d_in[21];
    const float* hw2   = (const float*)d_in[22];
    const float* hb2   = (const float*)d_in[23];
    float* ws  = (float*)d_ws;
    float* out = (float*)d_out;

    hipLaunchKernelGGL(k_pre, dim3(1 + NL), dim3(256), 0, stream,
                       tp, tw1, tb1, tw2, tb2, ew2, eb2, mw, mb, hw1, hb1, ws);
    hipLaunchKernelGGL(k_main, dim3(NN), dim3(512), 0, stream,
                       pos, adjp, nmask, pw, pb, ew1, eb1, aw1, ab1,
                       hw1, hw2, hb2, ws, out);
    hipLaunchKernelGGL(k_adj, dim3((NN/16)*((NN/16)+1)/2), dim3(256), 0, stream,
                       ws, nmask, aw2, ab2, out);
}